// Round 1
// baseline (1430.662 us; speedup 1.0000x reference)
//
#include <hip/hip_runtime.h>

#define N_PTS 32768
#define HID   100
#define STEPS 100
#define NPAIR 52   // hidden padded 100 -> 104, stored as 52 (j,j+1) pairs
#define LPP   13   // pairs per lane (4 lanes/point * 13 pairs * 2 j = 104)

// Output layout (concatenated flat, fp32):
#define OFF_Z     0
#define OFF_MUXZ  65536
#define OFF_LSXZ  163840
#define OFF_MUZX  262144
#define OFF_LTZX  327680
#define OFF_MUZ   360448
#define OFF_LTZ   425984

typedef float v2f __attribute__((ext_vector_type(2)));
typedef float v4f __attribute__((ext_vector_type(4)));

#if __has_builtin(__builtin_elementwise_fma)
#define FMA2(a, b, c) __builtin_elementwise_fma((a), (b), (c))
#else
#define FMA2(a, b, c) ((a) * (b) + (c))
#endif
#define LOv(q) __builtin_shufflevector((q), (q), 0, 1)
#define HIv(q) __builtin_shufflevector((q), (q), 2, 3)

__device__ __forceinline__ v2f splat(float x) { v2f r; r.x = x; r.y = x; return r; }

// Butterfly sum across a quad of lanes via DPP quad_perm (xor1=0xB1, xor2=0x4E).
__device__ __forceinline__ float qreduce(float v) {
  v += __int_as_float(__builtin_amdgcn_update_dpp(0, __float_as_int(v), 0xB1, 0xF, 0xF, true));
  v += __int_as_float(__builtin_amdgcn_update_dpp(0, __float_as_int(v), 0x4E, 0xF, 0xF, true));
  return v;
}
// horizontal (even/odd j partials) then quad reduce
__device__ __forceinline__ float hqreduce(v2f v) { return qreduce(v.x + v.y); }

// ---------------- Encoder: x -> h1 -> h2 -> (mu_zx, log_t_zx) ----------------
// Block = 256 threads = 4 waves covering 64 points; wave w handles h2 output
// chunk {26,26,24,24} at ob {0,26,52,76} (even offsets keep v2f loads aligned).
// 2048 waves total = 2 waves/SIMD (was 1 — the old kernel was latency-bound).
template<int NP>
__device__ __forceinline__ void enc_chunk(
    int ob, float x0, float x1, float x2,
    const float* __restrict__ We1, const float* __restrict__ be1,
    const float* __restrict__ We2, const float* __restrict__ be2,
    const float* __restrict__ Wmu, const float* __restrict__ Wlt,
    float& m0, float& m1, float& lt)
{
  v2f acc2[NP];
  #pragma unroll
  for (int i = 0; i < NP; ++i) acc2[i] = splat(0.f);

  #pragma unroll 2
  for (int k = 0; k < HID; k += 2) {
    const v2f w0 = *(const v2f*)(We1 + k);
    const v2f w1 = *(const v2f*)(We1 + HID + k);
    const v2f w2 = *(const v2f*)(We1 + 2*HID + k);
    const v2f bb = *(const v2f*)(be1 + k);
    // identical fma nesting to baseline, packed over the k-pair
    v2f aP = FMA2(splat(x0), w0, FMA2(splat(x1), w1, FMA2(splat(x2), w2, bb)));
    const float e0 = __expf(-aP.x), e1 = __expf(-aP.y);
    const float s0 = 1.f / (1.f + e0), s1 = 1.f / (1.f + e1);
    const v2f hh0 = splat(aP.x * s0);
    const v2f hh1 = splat(aP.y * s1);
    const v2f* r0 = (const v2f*)(We2 + k*HID + ob);        // 8B-aligned (even)
    const v2f* r1 = (const v2f*)(We2 + (k+1)*HID + ob);
    #pragma unroll
    for (int oo = 0; oo < NP; ++oo) {
      v2f tacc = FMA2(hh0, r0[oo], acc2[oo]);   // k then k+1: baseline order
      acc2[oo] = FMA2(hh1, r1[oo], tacc);
    }
  }

  m0 = 0.f; m1 = 0.f; lt = 0.f;
  #pragma unroll
  for (int oo = 0; oo < NP; ++oo) {
    #pragma unroll
    for (int h = 0; h < 2; ++h) {
      const int o = ob + 2*oo + h;
      float a   = (h ? acc2[oo].y : acc2[oo].x) + be2[o];
      float sig = 1.f / (1.f + __expf(-a));
      float h2  = a * sig;
      m0 = fmaf(h2, Wmu[o*2+0], m0);
      m1 = fmaf(h2, Wmu[o*2+1], m1);
      lt = fmaf(h2, Wlt[o],     lt);
    }
  }
}

__global__ __launch_bounds__(256, 2) void enc_kernel(
    const float* __restrict__ x,
    const float* __restrict__ We1, const float* __restrict__ be1,
    const float* __restrict__ We2, const float* __restrict__ be2,
    const float* __restrict__ Wmu, const float* __restrict__ bmu,
    const float* __restrict__ Wlt, const float* __restrict__ blt,
    const float* __restrict__ b_muz, const float* __restrict__ b_ltz,
    float* __restrict__ out)
{
  const int tid = threadIdx.x;
  const int w   = tid >> 6;           // wave 0..3
  const int pb  = tid & 63;           // point within block
  const int p   = blockIdx.x * 64 + pb;

  const float x0 = x[p*3+0], x1 = x[p*3+1], x2 = x[p*3+2];

  float m0, m1, lt;
  if (w < 2) enc_chunk<13>(w * 26,            x0, x1, x2, We1, be1, We2, be2, Wmu, Wlt, m0, m1, lt);
  else       enc_chunk<12>(52 + (w - 2) * 24, x0, x1, x2, We1, be1, We2, be2, Wmu, Wlt, m0, m1, lt);

  __shared__ float red[4][64][3];
  red[w][pb][0] = m0; red[w][pb][1] = m1; red[w][pb][2] = lt;
  __syncthreads();
  if (w == 0) {
    m0 += red[1][pb][0] + red[2][pb][0] + red[3][pb][0] + bmu[0];
    m1 += red[1][pb][1] + red[2][pb][1] + red[3][pb][1] + bmu[1];
    lt += red[1][pb][2] + red[2][pb][2] + red[3][pb][2] + blt[0];
    out[OFF_MUZX + p*2+0] = m0;
    out[OFF_MUZX + p*2+1] = m1;
    out[OFF_LTZX + p]     = lt;
    out[OFF_MUZ  + p*2+0] = b_muz[0];
    out[OFF_MUZ  + p*2+1] = b_muz[1];
    out[OFF_LTZ  + p]     = b_ltz[0];
  }
}

// ------------- SDE: 100 Euler-Maruyama steps on the pullback metric ----------
// Block = 256 threads = 64 points, 4 lanes per point; each lane owns 13 j-PAIRS
// (hidden padded to 104 with zero records — exact-zero contributions).
// LDS record per pair = 24 floats (96 B, 6 x ds_read_b128), all fields j-major
// pairs so v_pk ops consume loaded register pairs directly (no op_sel splats
// of LDS data; only loop-invariant z0/z1 get splatted):
//   {W0j0,W0j1, W1j0,W1j1 | bj0,bj1, W11j0,W11j1 | W00j0,W00j1, W01j0,W01j1 |
//    m0j0,m0j1, s0j0,s0j1 | m1j0,m1j1, s1j0,s1j1 | m2j0,m2j1, s2j0,s2j1}
// All 30 j-sums are independent v2f accumulators (even/odd-j partials) updated
// by v_pk_fma_f32; the whole swish'/swish'' setup is packed over the pair.
__global__ __launch_bounds__(256, 2) void sde_kernel(
    const float* __restrict__ Wd1,  const float* __restrict__ bd1,
    const float* __restrict__ Wdmu, const float* __restrict__ bdmu,
    const float* __restrict__ Wds,  const float* __restrict__ bds,
    const float* __restrict__ noise,
    float* __restrict__ out)
{
  __shared__ __align__(16) float wrec[NPAIR * 24];
  const int tid = threadIdx.x;
  for (int idx = tid; idx < NPAIR * 24; idx += 256) {
    const int pr = idx / 24, f = idx - pr * 24;
    const int j  = pr * 2 + (f & 1);
    const int g  = f >> 1;      // 0:W0 1:W1 2:b 3:W11 4:W00 5:W01 6..11:m/s
    float v = 0.f;
    if (j < HID) {
      const float w0 = Wd1[j], w1 = Wd1[HID + j];
      switch (g) {
        case 0:  v = w0; break;
        case 1:  v = w1; break;
        case 2:  v = bd1[j]; break;
        case 3:  v = w1 * w1; break;
        case 4:  v = w0 * w0; break;
        case 5:  v = w0 * w1; break;
        case 6:  v = Wdmu[j*3+0]; break;
        case 7:  v = Wds [j*3+0]; break;
        case 8:  v = Wdmu[j*3+1]; break;
        case 9:  v = Wds [j*3+1]; break;
        case 10: v = Wdmu[j*3+2]; break;
        default: v = Wds [j*3+2]; break;
      }
    }
    wrec[idx] = v;
  }
  __syncthreads();

  const int l     = tid & 3;                    // lane within quad
  const int p     = blockIdx.x * 64 + (tid >> 2);
  const int pbase = l * LPP;                    // lane's first pair
  const v4f* __restrict__ Rq = (const v4f*)wrec;   // 6 v4f per pair

  float z0 = out[OFF_MUZX + p*2+0];
  float z1 = out[OFF_MUZX + p*2+1];
  const float sdt = __expf(out[OFF_LTZX + p]) * 0.1f;  // sqrt(dt)

  const float2* __restrict__ noise2 = (const float2*)noise;

  for (int step = 0; step < STEPS; ++step) {
    // issue the noise load early; its latency hides under the j-loop
    const float2 nz = noise2[(size_t)step * N_PTS + p];

    v2f Jm[3][2], Js[3][2], Km[3][3], Ks[3][3];
    #pragma unroll
    for (int o = 0; o < 3; ++o) {
      Jm[o][0]=splat(0.f); Jm[o][1]=splat(0.f);
      Js[o][0]=splat(0.f); Js[o][1]=splat(0.f);
      Km[o][0]=splat(0.f); Km[o][1]=splat(0.f); Km[o][2]=splat(0.f);
      Ks[o][0]=splat(0.f); Ks[o][1]=splat(0.f); Ks[o][2]=splat(0.f);
    }
    const v2f z0P = splat(z0), z1P = splat(z1);

    #pragma unroll
    for (int t = 0; t < LPP; ++t) {
      const v4f* R = Rq + (pbase + t) * 6;
      const v4f A  = R[0];   // {W0j0,W0j1, W1j0,W1j1}
      const v4f B  = R[1];   // {bj0,bj1, W11j0,W11j1}
      const v4f Cq = R[2];   // {W00j0,W00j1, W01j0,W01j1}
      const v4f M0 = R[3], M1 = R[4], M2 = R[5];
      const v2f W0P  = LOv(A),  W1P  = HIv(A);
      const v2f bP   = LOv(B),  W11P = HIv(B);
      const v2f W00P = LOv(Cq), W01P = HIv(Cq);

      v2f aP = FMA2(z0P, W0P, FMA2(z1P, W1P, bP));
      v2f eP;   eP.x   = __expf(-aP.x);               eP.y   = __expf(-aP.y);
      v2f dP = splat(1.f) + eP;
      v2f sigP; sigP.x = __builtin_amdgcn_rcpf(dP.x); sigP.y = __builtin_amdgcn_rcpf(dP.y);
      const v2f t1P = splat(1.f) - sigP;
      const v2f ppP = sigP * t1P;
      const v2f uP  = FMA2(aP, ppP, sigP);                                   // swish'
      const v2f u2P = ppP * FMA2(aP, FMA2(splat(-2.f), sigP, splat(1.f)), splat(2.f)); // swish''
      const v2f c0  = uP  * W0P,  c1  = uP  * W1P;
      const v2f q00 = u2P * W00P, q01 = u2P * W01P, q11 = u2P * W11P;

      const v2f mP[3] = {LOv(M0), LOv(M1), LOv(M2)};
      const v2f sP[3] = {HIv(M0), HIv(M1), HIv(M2)};
      #pragma unroll
      for (int o = 0; o < 3; ++o) {
        Jm[o][0] = FMA2(c0,  mP[o], Jm[o][0]);
        Jm[o][1] = FMA2(c1,  mP[o], Jm[o][1]);
        Js[o][0] = FMA2(c0,  sP[o], Js[o][0]);
        Js[o][1] = FMA2(c1,  sP[o], Js[o][1]);
        Km[o][0] = FMA2(q00, mP[o], Km[o][0]);
        Km[o][1] = FMA2(q01, mP[o], Km[o][1]);
        Km[o][2] = FMA2(q11, mP[o], Km[o][2]);
        Ks[o][0] = FMA2(q00, sP[o], Ks[o][0]);
        Ks[o][1] = FMA2(q01, sP[o], Ks[o][1]);
        Ks[o][2] = FMA2(q11, sP[o], Ks[o][2]);
      }
    }

    // fold even/odd-j partials, then complete the j-sums across the quad
    float JmS[3][2], JsS[3][2], KmS[3][3], KsS[3][3];
    #pragma unroll
    for (int o = 0; o < 3; ++o) {
      JmS[o][0]=hqreduce(Jm[o][0]); JmS[o][1]=hqreduce(Jm[o][1]);
      JsS[o][0]=hqreduce(Js[o][0]); JsS[o][1]=hqreduce(Js[o][1]);
      KmS[o][0]=hqreduce(Km[o][0]); KmS[o][1]=hqreduce(Km[o][1]); KmS[o][2]=hqreduce(Km[o][2]);
      KsS[o][0]=hqreduce(Ks[o][0]); KsS[o][1]=hqreduce(Ks[o][1]); KsS[o][2]=hqreduce(Ks[o][2]);
    }

    // G = J^T J (2x2 sym)
    float G00=0.f, G01=0.f, G11=0.f;
    #pragma unroll
    for (int o = 0; o < 3; ++o) {
      G00 += JmS[o][0]*JmS[o][0] + JsS[o][0]*JsS[o][0];
      G01 += JmS[o][0]*JmS[o][1] + JsS[o][0]*JsS[o][1];
      G11 += JmS[o][1]*JmS[o][1] + JsS[o][1]*JsS[o][1];
    }
    // D[c][l] = dG[km]/dz_l (sym in k,m)
    float D00=0.f, D01=0.f, D10=0.f, D11=0.f, D20=0.f, D21=0.f;
    #pragma unroll
    for (int o = 0; o < 3; ++o) {
      D00 += 2.f*(KmS[o][0]*JmS[o][0] + KsS[o][0]*JsS[o][0]);
      D01 += 2.f*(KmS[o][1]*JmS[o][0] + KsS[o][1]*JsS[o][0]);
      D10 += KmS[o][0]*JmS[o][1] + JmS[o][0]*KmS[o][1] + KsS[o][0]*JsS[o][1] + JsS[o][0]*KsS[o][1];
      D11 += KmS[o][1]*JmS[o][1] + JmS[o][0]*KmS[o][2] + KsS[o][1]*JsS[o][1] + JsS[o][0]*KsS[o][2];
      D20 += 2.f*(KmS[o][1]*JmS[o][1] + KsS[o][1]*JsS[o][1]);
      D21 += 2.f*(KmS[o][2]*JmS[o][1] + KsS[o][2]*JsS[o][1]);
    }
    const float det = fmaf(G00, G11, -G01*G01);
    const float id  = __builtin_amdgcn_rcpf(det);
    const float i00 = G11*id, i01 = -G01*id, i11 = G00*id;
    // T[k,l,m] = Dg[k,m,l] + Dg[l,m,k] - Dg[k,l,m]
    const float T000 = D00;
    const float T001 = 2.f*D10 - D01;
    const float T010 = D01;
    const float T011 = D20;
    const float T110 = 2.f*D11 - D20;
    const float T111 = D21;
    // Chris[i][c] = 0.5 * ginv[i,m] T[k,l,m]
    const float C00 = 0.5f*(i00*T000 + i01*T001);
    const float C01 = 0.5f*(i00*T010 + i01*T011);
    const float C02 = 0.5f*(i00*T110 + i01*T111);
    const float C10 = 0.5f*(i01*T000 + i11*T001);
    const float C11 = 0.5f*(i01*T010 + i11*T011);
    const float C12 = 0.5f*(i01*T110 + i11*T111);
    // drift[i] = 0.5 * ginv[j,k] Chris[i,j,k]
    const float dr0 = 0.5f*(i00*C00 + 2.f*i01*C01 + i11*C02);
    const float dr1 = 0.5f*(i00*C10 + 2.f*i01*C11 + i11*C12);

    const float dw0 = sdt*nz.x, dw1 = sdt*nz.y;
    z0 += dr0 + i00*dw0 + i01*dw1;   // + ginv @ dW
    z1 += dr1 + i01*dw0 + i11*dw1;
  }

  // ---- final decode on z ----
  v2f MSm[3], MSs[3];
  #pragma unroll
  for (int o = 0; o < 3; ++o) { MSm[o] = splat(0.f); MSs[o] = splat(0.f); }
  const v2f zf0 = splat(z0), zf1 = splat(z1);
  #pragma unroll
  for (int t = 0; t < LPP; ++t) {
    const v4f* R = Rq + (pbase + t) * 6;
    const v4f A  = R[0];
    const v4f B  = R[1];
    const v4f M0 = R[3], M1 = R[4], M2 = R[5];
    v2f aP = FMA2(zf0, LOv(A), FMA2(zf1, HIv(A), LOv(B)));
    v2f eP;   eP.x   = __expf(-aP.x);               eP.y   = __expf(-aP.y);
    v2f dP = splat(1.f) + eP;
    v2f sigP; sigP.x = __builtin_amdgcn_rcpf(dP.x); sigP.y = __builtin_amdgcn_rcpf(dP.y);
    const v2f hP = aP * sigP;
    MSm[0] = FMA2(hP, LOv(M0), MSm[0]);  MSs[0] = FMA2(hP, HIv(M0), MSs[0]);
    MSm[1] = FMA2(hP, LOv(M1), MSm[1]);  MSs[1] = FMA2(hP, HIv(M1), MSs[1]);
    MSm[2] = FMA2(hP, LOv(M2), MSm[2]);  MSs[2] = FMA2(hP, HIv(M2), MSs[2]);
  }
  // reductions must run on all quad lanes (DPP reads masked lanes as 0)
  float mu[3], ls[3];
  #pragma unroll
  for (int o = 0; o < 3; ++o) { mu[o] = hqreduce(MSm[o]); ls[o] = hqreduce(MSs[o]); }

  if (l == 0) {
    out[OFF_Z + p*2+0] = z0;
    out[OFF_Z + p*2+1] = z1;
    #pragma unroll
    for (int o = 0; o < 3; ++o) {
      out[OFF_MUXZ + p*3 + o] = mu[o] + bdmu[o];
      out[OFF_LSXZ + p*3 + o] = ls[o] + bds[o];
    }
  }
}

extern "C" void kernel_launch(void* const* d_in, const int* in_sizes, int n_in,
                              void* d_out, int out_size, void* d_ws, size_t ws_size,
                              hipStream_t stream) {
  (void)in_sizes; (void)n_in; (void)d_ws; (void)ws_size; (void)out_size;
  const float* x    = (const float*)d_in[0];
  const float* We1  = (const float*)d_in[1];
  const float* be1  = (const float*)d_in[2];
  const float* We2  = (const float*)d_in[3];
  const float* be2  = (const float*)d_in[4];
  const float* Wmu  = (const float*)d_in[5];
  const float* bmu  = (const float*)d_in[6];
  const float* Wlt  = (const float*)d_in[7];
  const float* blt  = (const float*)d_in[8];
  const float* Wd1  = (const float*)d_in[9];
  const float* bd1  = (const float*)d_in[10];
  const float* Wdmu = (const float*)d_in[11];
  const float* bdmu = (const float*)d_in[12];
  const float* Wds  = (const float*)d_in[13];
  const float* bds  = (const float*)d_in[14];
  const float* bmz  = (const float*)d_in[15];
  const float* blz  = (const float*)d_in[16];
  const float* noise= (const float*)d_in[17];
  float* out = (float*)d_out;

  enc_kernel<<<512, 256, 0, stream>>>(x, We1, be1, We2, be2, Wmu, bmu, Wlt, blt,
                                      bmz, blz, out);
  sde_kernel<<<512, 256, 0, stream>>>(Wd1, bd1, Wdmu, bdmu, Wds, bds, noise, out);
}

// Round 4
// 571.057 us; speedup vs baseline: 2.5053x; 2.5053x over previous
//
#include <hip/hip_runtime.h>

#define N_PTS 32768
#define HID   100
#define STEPS 100
#define NPAIR 52   // hidden padded 100 -> 104, stored as 52 (j,j+1) pairs
#define LPP   13   // pairs per lane (4 lanes/point * 13 pairs * 2 j = 104)

// Output layout (concatenated flat, fp32):
#define OFF_Z     0
#define OFF_MUXZ  65536
#define OFF_LSXZ  163840
#define OFF_MUZX  262144
#define OFF_LTZX  327680
#define OFF_MUZ   360448
#define OFF_LTZ   425984

typedef float v2f __attribute__((ext_vector_type(2)));
typedef float v4f __attribute__((ext_vector_type(4)));

#if __has_builtin(__builtin_elementwise_fma)
#define FMA2(a, b, c) __builtin_elementwise_fma((a), (b), (c))
#else
#define FMA2(a, b, c) ((a) * (b) + (c))
#endif
#define LOv(q) __builtin_shufflevector((q), (q), 0, 1)
#define HIv(q) __builtin_shufflevector((q), (q), 2, 3)

__device__ __forceinline__ v2f splat(float x) { v2f r; r.x = x; r.y = x; return r; }

// Butterfly sum across a quad of lanes via DPP quad_perm (xor1=0xB1, xor2=0x4E).
__device__ __forceinline__ float qreduce(float v) {
  v += __int_as_float(__builtin_amdgcn_update_dpp(0, __float_as_int(v), 0xB1, 0xF, 0xF, true));
  v += __int_as_float(__builtin_amdgcn_update_dpp(0, __float_as_int(v), 0x4E, 0xF, 0xF, true));
  return v;
}
// horizontal (even/odd j partials) then quad reduce
__device__ __forceinline__ float hqreduce(v2f v) { return qreduce(v.x + v.y); }

// ---------------- Encoder: x -> h1 -> h2 -> (mu_zx, log_t_zx) ----------------
// Block = 256 threads = 4 waves covering 64 points; wave w handles h2 output
// chunk {26,26,24,24} at ob {0,26,52,76} (even offsets keep v2f loads aligned).
template<int NP>
__device__ __forceinline__ void enc_chunk(
    int ob, float x0, float x1, float x2,
    const float* __restrict__ We1, const float* __restrict__ be1,
    const float* __restrict__ We2, const float* __restrict__ be2,
    const float* __restrict__ Wmu, const float* __restrict__ Wlt,
    float& m0, float& m1, float& lt)
{
  v2f acc2[NP];
  #pragma unroll
  for (int i = 0; i < NP; ++i) acc2[i] = splat(0.f);

  #pragma unroll 2
  for (int k = 0; k < HID; k += 2) {
    const v2f w0 = *(const v2f*)(We1 + k);
    const v2f w1 = *(const v2f*)(We1 + HID + k);
    const v2f w2 = *(const v2f*)(We1 + 2*HID + k);
    const v2f bb = *(const v2f*)(be1 + k);
    // identical fma nesting to baseline, packed over the k-pair
    v2f aP = FMA2(splat(x0), w0, FMA2(splat(x1), w1, FMA2(splat(x2), w2, bb)));
    const float e0 = __expf(-aP.x), e1 = __expf(-aP.y);
    const float s0 = 1.f / (1.f + e0), s1 = 1.f / (1.f + e1);
    const v2f hh0 = splat(aP.x * s0);
    const v2f hh1 = splat(aP.y * s1);
    const v2f* r0 = (const v2f*)(We2 + k*HID + ob);        // 8B-aligned (even)
    const v2f* r1 = (const v2f*)(We2 + (k+1)*HID + ob);
    #pragma unroll
    for (int oo = 0; oo < NP; ++oo) {
      v2f tacc = FMA2(hh0, r0[oo], acc2[oo]);   // k then k+1: baseline order
      acc2[oo] = FMA2(hh1, r1[oo], tacc);
    }
  }

  m0 = 0.f; m1 = 0.f; lt = 0.f;
  #pragma unroll
  for (int oo = 0; oo < NP; ++oo) {
    #pragma unroll
    for (int h = 0; h < 2; ++h) {
      const int o = ob + 2*oo + h;
      float a   = (h ? acc2[oo].y : acc2[oo].x) + be2[o];
      float sig = 1.f / (1.f + __expf(-a));
      float h2  = a * sig;
      m0 = fmaf(h2, Wmu[o*2+0], m0);
      m1 = fmaf(h2, Wmu[o*2+1], m1);
      lt = fmaf(h2, Wlt[o],     lt);
    }
  }
}

__global__ __launch_bounds__(256, 2) void enc_kernel(
    const float* __restrict__ x,
    const float* __restrict__ We1, const float* __restrict__ be1,
    const float* __restrict__ We2, const float* __restrict__ be2,
    const float* __restrict__ Wmu, const float* __restrict__ bmu,
    const float* __restrict__ Wlt, const float* __restrict__ blt,
    const float* __restrict__ b_muz, const float* __restrict__ b_ltz,
    float* __restrict__ out)
{
  const int tid = threadIdx.x;
  const int w   = tid >> 6;           // wave 0..3
  const int pb  = tid & 63;           // point within block
  const int p   = blockIdx.x * 64 + pb;

  const float x0 = x[p*3+0], x1 = x[p*3+1], x2 = x[p*3+2];

  float m0, m1, lt;
  if (w < 2) enc_chunk<13>(w * 26,            x0, x1, x2, We1, be1, We2, be2, Wmu, Wlt, m0, m1, lt);
  else       enc_chunk<12>(52 + (w - 2) * 24, x0, x1, x2, We1, be1, We2, be2, Wmu, Wlt, m0, m1, lt);

  __shared__ float red[4][64][3];
  red[w][pb][0] = m0; red[w][pb][1] = m1; red[w][pb][2] = lt;
  __syncthreads();
  if (w == 0) {
    m0 += red[1][pb][0] + red[2][pb][0] + red[3][pb][0] + bmu[0];
    m1 += red[1][pb][1] + red[2][pb][1] + red[3][pb][1] + bmu[1];
    lt += red[1][pb][2] + red[2][pb][2] + red[3][pb][2] + blt[0];
    out[OFF_MUZX + p*2+0] = m0;
    out[OFF_MUZX + p*2+1] = m1;
    out[OFF_LTZX + p]     = lt;
    out[OFF_MUZ  + p*2+0] = b_muz[0];
    out[OFF_MUZ  + p*2+1] = b_muz[1];
    out[OFF_LTZ  + p]     = b_ltz[0];
  }
}

// ------------- SDE: 100 Euler-Maruyama steps on the pullback metric ----------
// Block = 256 threads = 64 points, 4 lanes per point; each lane owns 13 j-PAIRS
// (hidden padded to 104 with zero records — exact-zero contributions).
// LDS record per pair = 24 floats (96 B, 6 x ds_read_b128), all fields j-major
// pairs so v_pk ops consume loaded register pairs directly:
//   {W0j0,W0j1, W1j0,W1j1 | bj0,bj1, W11j0,W11j1 | W00j0,W00j1, W01j0,W01j1 |
//    m0j0,m0j1, s0j0,s0j1 | m1j0,m1j1, s1j0,s1j1 | m2j0,m2j1, s2j0,s2j1}
// CRITICAL: the pair loop must stay ROLLED (partial unroll only). Fully
// unrolling it makes all 78 ds_reads loop-invariant in the step loop; LICM
// then hoists ~312 dwords of LDS into registers, regalloc spills them to
// scratch, and the step loop re-reads ~337 B/lane/step from scratch instead
// of LDS (round-1 post-mortem: FETCH_SIZE 13 MB -> 4.13 GB, VALUBusy 78->25%).
__global__ __launch_bounds__(256, 2) void sde_kernel(
    const float* __restrict__ Wd1,  const float* __restrict__ bd1,
    const float* __restrict__ Wdmu, const float* __restrict__ bdmu,
    const float* __restrict__ Wds,  const float* __restrict__ bds,
    const float* __restrict__ noise,
    float* __restrict__ out)
{
  __shared__ __align__(16) float wrec[NPAIR * 24];
  const int tid = threadIdx.x;
  for (int idx = tid; idx < NPAIR * 24; idx += 256) {
    const int pr = idx / 24, f = idx - pr * 24;
    const int j  = pr * 2 + (f & 1);
    const int g  = f >> 1;      // 0:W0 1:W1 2:b 3:W11 4:W00 5:W01 6..11:m/s
    float v = 0.f;
    if (j < HID) {
      const float w0 = Wd1[j], w1 = Wd1[HID + j];
      switch (g) {
        case 0:  v = w0; break;
        case 1:  v = w1; break;
        case 2:  v = bd1[j]; break;
        case 3:  v = w1 * w1; break;
        case 4:  v = w0 * w0; break;
        case 5:  v = w0 * w1; break;
        case 6:  v = Wdmu[j*3+0]; break;
        case 7:  v = Wds [j*3+0]; break;
        case 8:  v = Wdmu[j*3+1]; break;
        case 9:  v = Wds [j*3+1]; break;
        case 10: v = Wdmu[j*3+2]; break;
        default: v = Wds [j*3+2]; break;
      }
    }
    wrec[idx] = v;
  }
  __syncthreads();

  const int l     = tid & 3;                    // lane within quad
  const int p     = blockIdx.x * 64 + (tid >> 2);
  const int pbase = l * LPP;                    // lane's first pair
  const v4f* __restrict__ Rq = (const v4f*)wrec;   // 6 v4f per pair

  float z0 = out[OFF_MUZX + p*2+0];
  float z1 = out[OFF_MUZX + p*2+1];
  const float sdt = __expf(out[OFF_LTZX + p]) * 0.1f;  // sqrt(dt)

  const float2* __restrict__ noise2 = (const float2*)noise;

  for (int step = 0; step < STEPS; ++step) {
    // issue the noise load early; its latency hides under the j-loop
    const float2 nz = noise2[(size_t)step * N_PTS + p];

    v2f Jm[3][2], Js[3][2], Km[3][3], Ks[3][3];
    #pragma unroll
    for (int o = 0; o < 3; ++o) {
      Jm[o][0]=splat(0.f); Jm[o][1]=splat(0.f);
      Js[o][0]=splat(0.f); Js[o][1]=splat(0.f);
      Km[o][0]=splat(0.f); Km[o][1]=splat(0.f); Km[o][2]=splat(0.f);
      Ks[o][0]=splat(0.f); Ks[o][1]=splat(0.f); Ks[o][2]=splat(0.f);
    }
    const v2f z0P = splat(z0), z1P = splat(z1);

    // ROLLED loop (unroll 2 only) with loop-carried pointer: keeps the
    // ds_reads inside the step loop body (see comment above the kernel).
    const v4f* R = Rq + pbase * 6;
    #pragma unroll 2
    for (int t = 0; t < LPP; ++t, R += 6) {
      const v4f A  = R[0];   // {W0j0,W0j1, W1j0,W1j1}
      const v4f B  = R[1];   // {bj0,bj1, W11j0,W11j1}
      const v4f Cq = R[2];   // {W00j0,W00j1, W01j0,W01j1}
      const v4f M0 = R[3], M1 = R[4], M2 = R[5];
      const v2f W0P  = LOv(A),  W1P  = HIv(A);
      const v2f bP   = LOv(B),  W11P = HIv(B);
      const v2f W00P = LOv(Cq), W01P = HIv(Cq);

      v2f aP = FMA2(z0P, W0P, FMA2(z1P, W1P, bP));
      v2f eP;   eP.x   = __expf(-aP.x);               eP.y   = __expf(-aP.y);
      v2f dP = splat(1.f) + eP;
      v2f sigP; sigP.x = __builtin_amdgcn_rcpf(dP.x); sigP.y = __builtin_amdgcn_rcpf(dP.y);
      const v2f t1P = splat(1.f) - sigP;
      const v2f ppP = sigP * t1P;
      const v2f uP  = FMA2(aP, ppP, sigP);                                   // swish'
      const v2f u2P = ppP * FMA2(aP, FMA2(splat(-2.f), sigP, splat(1.f)), splat(2.f)); // swish''
      const v2f c0  = uP  * W0P,  c1  = uP  * W1P;
      const v2f q00 = u2P * W00P, q01 = u2P * W01P, q11 = u2P * W11P;

      const v2f mP0 = LOv(M0), mP1 = LOv(M1), mP2 = LOv(M2);
      const v2f sP0 = HIv(M0), sP1 = HIv(M1), sP2 = HIv(M2);

      Jm[0][0] = FMA2(c0,  mP0, Jm[0][0]);  Jm[0][1] = FMA2(c1,  mP0, Jm[0][1]);
      Js[0][0] = FMA2(c0,  sP0, Js[0][0]);  Js[0][1] = FMA2(c1,  sP0, Js[0][1]);
      Km[0][0] = FMA2(q00, mP0, Km[0][0]);  Km[0][1] = FMA2(q01, mP0, Km[0][1]);
      Km[0][2] = FMA2(q11, mP0, Km[0][2]);
      Ks[0][0] = FMA2(q00, sP0, Ks[0][0]);  Ks[0][1] = FMA2(q01, sP0, Ks[0][1]);
      Ks[0][2] = FMA2(q11, sP0, Ks[0][2]);

      Jm[1][0] = FMA2(c0,  mP1, Jm[1][0]);  Jm[1][1] = FMA2(c1,  mP1, Jm[1][1]);
      Js[1][0] = FMA2(c0,  sP1, Js[1][0]);  Js[1][1] = FMA2(c1,  sP1, Js[1][1]);
      Km[1][0] = FMA2(q00, mP1, Km[1][0]);  Km[1][1] = FMA2(q01, mP1, Km[1][1]);
      Km[1][2] = FMA2(q11, mP1, Km[1][2]);
      Ks[1][0] = FMA2(q00, sP1, Ks[1][0]);  Ks[1][1] = FMA2(q01, sP1, Ks[1][1]);
      Ks[1][2] = FMA2(q11, sP1, Ks[1][2]);

      Jm[2][0] = FMA2(c0,  mP2, Jm[2][0]);  Jm[2][1] = FMA2(c1,  mP2, Jm[2][1]);
      Js[2][0] = FMA2(c0,  sP2, Js[2][0]);  Js[2][1] = FMA2(c1,  sP2, Js[2][1]);
      Km[2][0] = FMA2(q00, mP2, Km[2][0]);  Km[2][1] = FMA2(q01, mP2, Km[2][1]);
      Km[2][2] = FMA2(q11, mP2, Km[2][2]);
      Ks[2][0] = FMA2(q00, sP2, Ks[2][0]);  Ks[2][1] = FMA2(q01, sP2, Ks[2][1]);
      Ks[2][2] = FMA2(q11, sP2, Ks[2][2]);
    }

    // fold even/odd-j partials, then complete the j-sums across the quad
    float JmS[3][2], JsS[3][2], KmS[3][3], KsS[3][3];
    #pragma unroll
    for (int o = 0; o < 3; ++o) {
      JmS[o][0]=hqreduce(Jm[o][0]); JmS[o][1]=hqreduce(Jm[o][1]);
      JsS[o][0]=hqreduce(Js[o][0]); JsS[o][1]=hqreduce(Js[o][1]);
      KmS[o][0]=hqreduce(Km[o][0]); KmS[o][1]=hqreduce(Km[o][1]); KmS[o][2]=hqreduce(Km[o][2]);
      KsS[o][0]=hqreduce(Ks[o][0]); KsS[o][1]=hqreduce(Ks[o][1]); KsS[o][2]=hqreduce(Ks[o][2]);
    }

    // G = J^T J (2x2 sym)
    float G00=0.f, G01=0.f, G11=0.f;
    #pragma unroll
    for (int o = 0; o < 3; ++o) {
      G00 += JmS[o][0]*JmS[o][0] + JsS[o][0]*JsS[o][0];
      G01 += JmS[o][0]*JmS[o][1] + JsS[o][0]*JsS[o][1];
      G11 += JmS[o][1]*JmS[o][1] + JsS[o][1]*JsS[o][1];
    }
    // D[c][l] = dG[km]/dz_l (sym in k,m)
    float D00=0.f, D01=0.f, D10=0.f, D11=0.f, D20=0.f, D21=0.f;
    #pragma unroll
    for (int o = 0; o < 3; ++o) {
      D00 += 2.f*(KmS[o][0]*JmS[o][0] + KsS[o][0]*JsS[o][0]);
      D01 += 2.f*(KmS[o][1]*JmS[o][0] + KsS[o][1]*JsS[o][0]);
      D10 += KmS[o][0]*JmS[o][1] + JmS[o][0]*KmS[o][1] + KsS[o][0]*JsS[o][1] + JsS[o][0]*KsS[o][1];
      D11 += KmS[o][1]*JmS[o][1] + JmS[o][0]*KmS[o][2] + KsS[o][1]*JsS[o][1] + JsS[o][0]*KsS[o][2];
      D20 += 2.f*(KmS[o][1]*JmS[o][1] + KsS[o][1]*JsS[o][1]);
      D21 += 2.f*(KmS[o][2]*JmS[o][1] + KsS[o][2]*JsS[o][1]);
    }
    const float det = fmaf(G00, G11, -G01*G01);
    const float id  = __builtin_amdgcn_rcpf(det);
    const float i00 = G11*id, i01 = -G01*id, i11 = G00*id;
    // T[k,l,m] = Dg[k,m,l] + Dg[l,m,k] - Dg[k,l,m]
    const float T000 = D00;
    const float T001 = 2.f*D10 - D01;
    const float T010 = D01;
    const float T011 = D20;
    const float T110 = 2.f*D11 - D20;
    const float T111 = D21;
    // Chris[i][c] = 0.5 * ginv[i,m] T[k,l,m]
    const float C00 = 0.5f*(i00*T000 + i01*T001);
    const float C01 = 0.5f*(i00*T010 + i01*T011);
    const float C02 = 0.5f*(i00*T110 + i01*T111);
    const float C10 = 0.5f*(i01*T000 + i11*T001);
    const float C11 = 0.5f*(i01*T010 + i11*T011);
    const float C12 = 0.5f*(i01*T110 + i11*T111);
    // drift[i] = 0.5 * ginv[j,k] Chris[i,j,k]
    const float dr0 = 0.5f*(i00*C00 + 2.f*i01*C01 + i11*C02);
    const float dr1 = 0.5f*(i00*C10 + 2.f*i01*C11 + i11*C12);

    const float dw0 = sdt*nz.x, dw1 = sdt*nz.y;
    z0 += dr0 + i00*dw0 + i01*dw1;   // + ginv @ dW
    z1 += dr1 + i01*dw0 + i11*dw1;
  }

  // ---- final decode on z ----
  v2f MSm[3], MSs[3];
  #pragma unroll
  for (int o = 0; o < 3; ++o) { MSm[o] = splat(0.f); MSs[o] = splat(0.f); }
  const v2f zf0 = splat(z0), zf1 = splat(z1);
  {
    const v4f* R = Rq + pbase * 6;
    #pragma unroll 2
    for (int t = 0; t < LPP; ++t, R += 6) {
      const v4f A  = R[0];
      const v4f B  = R[1];
      const v4f M0 = R[3], M1 = R[4], M2 = R[5];
      v2f aP = FMA2(zf0, LOv(A), FMA2(zf1, HIv(A), LOv(B)));
      v2f eP;   eP.x   = __expf(-aP.x);               eP.y   = __expf(-aP.y);
      v2f dP = splat(1.f) + eP;
      v2f sigP; sigP.x = __builtin_amdgcn_rcpf(dP.x); sigP.y = __builtin_amdgcn_rcpf(dP.y);
      const v2f hP = aP * sigP;
      MSm[0] = FMA2(hP, LOv(M0), MSm[0]);  MSs[0] = FMA2(hP, HIv(M0), MSs[0]);
      MSm[1] = FMA2(hP, LOv(M1), MSm[1]);  MSs[1] = FMA2(hP, HIv(M1), MSs[1]);
      MSm[2] = FMA2(hP, LOv(M2), MSm[2]);  MSs[2] = FMA2(hP, HIv(M2), MSs[2]);
    }
  }
  // reductions must run on all quad lanes (DPP reads masked lanes as 0)
  float mu[3], ls[3];
  #pragma unroll
  for (int o = 0; o < 3; ++o) { mu[o] = hqreduce(MSm[o]); ls[o] = hqreduce(MSs[o]); }

  if (l == 0) {
    out[OFF_Z + p*2+0] = z0;
    out[OFF_Z + p*2+1] = z1;
    #pragma unroll
    for (int o = 0; o < 3; ++o) {
      out[OFF_MUXZ + p*3 + o] = mu[o] + bdmu[o];
      out[OFF_LSXZ + p*3 + o] = ls[o] + bds[o];
    }
  }
}

extern "C" void kernel_launch(void* const* d_in, const int* in_sizes, int n_in,
                              void* d_out, int out_size, void* d_ws, size_t ws_size,
                              hipStream_t stream) {
  (void)in_sizes; (void)n_in; (void)d_ws; (void)ws_size; (void)out_size;
  const float* x    = (const float*)d_in[0];
  const float* We1  = (const float*)d_in[1];
  const float* be1  = (const float*)d_in[2];
  const float* We2  = (const float*)d_in[3];
  const float* be2  = (const float*)d_in[4];
  const float* Wmu  = (const float*)d_in[5];
  const float* bmu  = (const float*)d_in[6];
  const float* Wlt  = (const float*)d_in[7];
  const float* blt  = (const float*)d_in[8];
  const float* Wd1  = (const float*)d_in[9];
  const float* bd1  = (const float*)d_in[10];
  const float* Wdmu = (const float*)d_in[11];
  const float* bdmu = (const float*)d_in[12];
  const float* Wds  = (const float*)d_in[13];
  const float* bds  = (const float*)d_in[14];
  const float* bmz  = (const float*)d_in[15];
  const float* blz  = (const float*)d_in[16];
  const float* noise= (const float*)d_in[17];
  float* out = (float*)d_out;

  enc_kernel<<<512, 256, 0, stream>>>(x, We1, be1, We2, be2, Wmu, bmu, Wlt, blt,
                                      bmz, blz, out);
  sde_kernel<<<512, 256, 0, stream>>>(Wd1, bd1, Wdmu, bdmu, Wds, bds, noise, out);
}

// Round 5
// 570.099 us; speedup vs baseline: 2.5095x; 1.0017x over previous
//
#include <hip/hip_runtime.h>

#define N_PTS 32768
#define HID   100
#define STEPS 100
#define NPAIR 52   // hidden padded 100 -> 104, stored as 52 (j,j+1) pairs
#define LPP   13   // pairs per lane (4 lanes/point * 13 pairs * 2 j = 104)

// Output layout (concatenated flat, fp32):
#define OFF_Z     0
#define OFF_MUXZ  65536
#define OFF_LSXZ  163840
#define OFF_MUZX  262144
#define OFF_LTZX  327680
#define OFF_MUZ   360448
#define OFF_LTZ   425984

typedef float v2f __attribute__((ext_vector_type(2)));
typedef float v4f __attribute__((ext_vector_type(4)));

#if __has_builtin(__builtin_elementwise_fma)
#define FMA2(a, b, c) __builtin_elementwise_fma((a), (b), (c))
#else
#define FMA2(a, b, c) ((a) * (b) + (c))
#endif
#define LOv(q) __builtin_shufflevector((q), (q), 0, 1)
#define HIv(q) __builtin_shufflevector((q), (q), 2, 3)

__device__ __forceinline__ v2f splat(float x) { v2f r; r.x = x; r.y = x; return r; }

// Butterfly sum across a quad of lanes via DPP quad_perm (xor1=0xB1, xor2=0x4E).
__device__ __forceinline__ float qreduce(float v) {
  v += __int_as_float(__builtin_amdgcn_update_dpp(0, __float_as_int(v), 0xB1, 0xF, 0xF, true));
  v += __int_as_float(__builtin_amdgcn_update_dpp(0, __float_as_int(v), 0x4E, 0xF, 0xF, true));
  return v;
}
// horizontal (even/odd j partials) then quad reduce
__device__ __forceinline__ float hqreduce(v2f v) { return qreduce(v.x + v.y); }

// ---------------- Encoder chunk: x -> h1 -> h2 partial -> (m0,m1,lt) ----------
// Wave w handles h2 output chunk {26,26,24,24} at ob {0,26,52,76} (even offsets
// keep v2f loads aligned).
template<int NP>
__device__ __forceinline__ void enc_chunk(
    int ob, float x0, float x1, float x2,
    const float* __restrict__ We1, const float* __restrict__ be1,
    const float* __restrict__ We2, const float* __restrict__ be2,
    const float* __restrict__ Wmu, const float* __restrict__ Wlt,
    float& m0, float& m1, float& lt)
{
  v2f acc2[NP];
  #pragma unroll
  for (int i = 0; i < NP; ++i) acc2[i] = splat(0.f);

  #pragma unroll 2
  for (int k = 0; k < HID; k += 2) {
    const v2f w0 = *(const v2f*)(We1 + k);
    const v2f w1 = *(const v2f*)(We1 + HID + k);
    const v2f w2 = *(const v2f*)(We1 + 2*HID + k);
    const v2f bb = *(const v2f*)(be1 + k);
    // identical fma nesting to baseline, packed over the k-pair
    v2f aP = FMA2(splat(x0), w0, FMA2(splat(x1), w1, FMA2(splat(x2), w2, bb)));
    const float e0 = __expf(-aP.x), e1 = __expf(-aP.y);
    const float s0 = 1.f / (1.f + e0), s1 = 1.f / (1.f + e1);
    const v2f hh0 = splat(aP.x * s0);
    const v2f hh1 = splat(aP.y * s1);
    const v2f* r0 = (const v2f*)(We2 + k*HID + ob);        // 8B-aligned (even)
    const v2f* r1 = (const v2f*)(We2 + (k+1)*HID + ob);
    #pragma unroll
    for (int oo = 0; oo < NP; ++oo) {
      v2f tacc = FMA2(hh0, r0[oo], acc2[oo]);   // k then k+1: baseline order
      acc2[oo] = FMA2(hh1, r1[oo], tacc);
    }
  }

  m0 = 0.f; m1 = 0.f; lt = 0.f;
  #pragma unroll
  for (int oo = 0; oo < NP; ++oo) {
    #pragma unroll
    for (int h = 0; h < 2; ++h) {
      const int o = ob + 2*oo + h;
      float a   = (h ? acc2[oo].y : acc2[oo].x) + be2[o];
      float sig = 1.f / (1.f + __expf(-a));
      float h2  = a * sig;
      m0 = fmaf(h2, Wmu[o*2+0], m0);
      m1 = fmaf(h2, Wmu[o*2+1], m1);
      lt = fmaf(h2, Wlt[o],     lt);
    }
  }
}

// ---------------- Fused kernel: encoder -> SDE -> final decode ----------------
// Block = 256 threads = 64 points. Phase 1 (encoder): 4 waves each compute a
// partial h2 chunk for all 64 points; quad-sum via LDS; mu/lt pass to phase 2
// through LDS (no global round-trip, no second launch).
// Phase 2 (SDE): 4 lanes per point; each lane owns 13 j-PAIRS (hidden padded
// to 104 with zero records — exact-zero contributions through swish derivs).
// LDS record per pair = 24 floats (96 B, 6 x ds_read_b128), j-major pairs so
// v_pk ops consume loaded register pairs directly:
//   {W0j0,W0j1, W1j0,W1j1 | bj0,bj1, W11j0,W11j1 | W00j0,W00j1, W01j0,W01j1 |
//    m0j0,m0j1, s0j0,s0j1 | m1j0,m1j1, s1j0,s1j1 | m2j0,m2j1, s2j0,s2j1}
// CRITICAL: the pair loop must stay ROLLED (partial unroll only). Fully
// unrolling it makes all 78 ds_reads loop-invariant in the step loop; LICM
// hoists ~312 dwords of LDS into registers, regalloc spills to scratch, and
// the step loop re-reads scratch instead of LDS (round-1 post-mortem:
// FETCH_SIZE 13 MB -> 4.13 GB, VALUBusy 78 -> 25%). unroll 4 keeps the loop
// alive while widening the ds_read prefetch window (24 loads in flight).
__global__ __launch_bounds__(256, 2) void vaebm_kernel(
    const float* __restrict__ x,
    const float* __restrict__ We1, const float* __restrict__ be1,
    const float* __restrict__ We2, const float* __restrict__ be2,
    const float* __restrict__ Wmu, const float* __restrict__ bmu,
    const float* __restrict__ Wlt, const float* __restrict__ blt,
    const float* __restrict__ Wd1,  const float* __restrict__ bd1,
    const float* __restrict__ Wdmu, const float* __restrict__ bdmu,
    const float* __restrict__ Wds,  const float* __restrict__ bds,
    const float* __restrict__ b_muz, const float* __restrict__ b_ltz,
    const float* __restrict__ noise,
    float* __restrict__ out)
{
  __shared__ __align__(16) float wrec[NPAIR * 24];
  __shared__ float red[4][64][3];
  __shared__ float zlds[64][3];

  const int tid = threadIdx.x;

  // ---- SDE weight-record fill (independent of encoder; loads overlap it) ----
  for (int idx = tid; idx < NPAIR * 24; idx += 256) {
    const int pr = idx / 24, f = idx - pr * 24;
    const int j  = pr * 2 + (f & 1);
    const int g  = f >> 1;      // 0:W0 1:W1 2:b 3:W11 4:W00 5:W01 6..11:m/s
    float v = 0.f;
    if (j < HID) {
      const float w0 = Wd1[j], w1 = Wd1[HID + j];
      switch (g) {
        case 0:  v = w0; break;
        case 1:  v = w1; break;
        case 2:  v = bd1[j]; break;
        case 3:  v = w1 * w1; break;
        case 4:  v = w0 * w0; break;
        case 5:  v = w0 * w1; break;
        case 6:  v = Wdmu[j*3+0]; break;
        case 7:  v = Wds [j*3+0]; break;
        case 8:  v = Wdmu[j*3+1]; break;
        case 9:  v = Wds [j*3+1]; break;
        case 10: v = Wdmu[j*3+2]; break;
        default: v = Wds [j*3+2]; break;
      }
    }
    wrec[idx] = v;
  }

  // ---- Phase 1: encoder ----
  const int w  = tid >> 6;            // wave 0..3
  const int pb = tid & 63;            // point within block
  const int p  = blockIdx.x * 64 + pb;

  const float x0 = x[p*3+0], x1 = x[p*3+1], x2 = x[p*3+2];

  float m0, m1, lt;
  if (w < 2) enc_chunk<13>(w * 26,            x0, x1, x2, We1, be1, We2, be2, Wmu, Wlt, m0, m1, lt);
  else       enc_chunk<12>(52 + (w - 2) * 24, x0, x1, x2, We1, be1, We2, be2, Wmu, Wlt, m0, m1, lt);

  red[w][pb][0] = m0; red[w][pb][1] = m1; red[w][pb][2] = lt;
  __syncthreads();
  if (w == 0) {
    m0 += red[1][pb][0] + red[2][pb][0] + red[3][pb][0] + bmu[0];
    m1 += red[1][pb][1] + red[2][pb][1] + red[3][pb][1] + bmu[1];
    lt += red[1][pb][2] + red[2][pb][2] + red[3][pb][2] + blt[0];
    out[OFF_MUZX + p*2+0] = m0;
    out[OFF_MUZX + p*2+1] = m1;
    out[OFF_LTZX + p]     = lt;
    out[OFF_MUZ  + p*2+0] = b_muz[0];
    out[OFF_MUZ  + p*2+1] = b_muz[1];
    out[OFF_LTZ  + p]     = b_ltz[0];
    zlds[pb][0] = m0; zlds[pb][1] = m1; zlds[pb][2] = lt;
  }
  __syncthreads();

  // ---- Phase 2: SDE (100 Euler-Maruyama steps on the pullback metric) ----
  const int l     = tid & 3;                    // lane within quad
  const int pt    = tid >> 2;                   // point within block
  const int pg    = blockIdx.x * 64 + pt;       // global point
  const int pbase = l * LPP;                    // lane's first pair
  const v4f* __restrict__ Rq = (const v4f*)wrec;   // 6 v4f per pair

  float z0 = zlds[pt][0];
  float z1 = zlds[pt][1];
  const float sdt = __expf(zlds[pt][2]) * 0.1f;  // sqrt(dt) = exp(lt)/sqrt(100)

  const float2* __restrict__ noise2 = (const float2*)noise;

  for (int step = 0; step < STEPS; ++step) {
    // issue the noise load early; its latency hides under the j-loop
    const float2 nz = noise2[(size_t)step * N_PTS + pg];

    v2f Jm[3][2], Js[3][2], Km[3][3], Ks[3][3];
    #pragma unroll
    for (int o = 0; o < 3; ++o) {
      Jm[o][0]=splat(0.f); Jm[o][1]=splat(0.f);
      Js[o][0]=splat(0.f); Js[o][1]=splat(0.f);
      Km[o][0]=splat(0.f); Km[o][1]=splat(0.f); Km[o][2]=splat(0.f);
      Ks[o][0]=splat(0.f); Ks[o][1]=splat(0.f); Ks[o][2]=splat(0.f);
    }
    const v2f z0P = splat(z0), z1P = splat(z1);

    // ROLLED loop (partial unroll) with loop-carried pointer: keeps the
    // ds_reads inside the step loop body (see comment above the kernel).
    const v4f* R = Rq + pbase * 6;
    #pragma unroll 4
    for (int t = 0; t < LPP; ++t, R += 6) {
      const v4f A  = R[0];   // {W0j0,W0j1, W1j0,W1j1}
      const v4f B  = R[1];   // {bj0,bj1, W11j0,W11j1}
      const v4f Cq = R[2];   // {W00j0,W00j1, W01j0,W01j1}
      const v4f M0 = R[3], M1 = R[4], M2 = R[5];
      const v2f W0P  = LOv(A),  W1P  = HIv(A);
      const v2f bP   = LOv(B),  W11P = HIv(B);
      const v2f W00P = LOv(Cq), W01P = HIv(Cq);

      v2f aP = FMA2(z0P, W0P, FMA2(z1P, W1P, bP));
      v2f eP;   eP.x   = __expf(-aP.x);               eP.y   = __expf(-aP.y);
      v2f dP = splat(1.f) + eP;
      v2f sigP; sigP.x = __builtin_amdgcn_rcpf(dP.x); sigP.y = __builtin_amdgcn_rcpf(dP.y);
      const v2f ppP  = FMA2(-sigP, sigP, sigP);                 // sig(1-sig)
      const v2f uP   = FMA2(aP, ppP, sigP);                     // swish'
      const v2f w2sP = FMA2(splat(-2.f), sigP, splat(1.f));     // 1-2sig
      const v2f u2P  = FMA2(uP, w2sP, sigP);  // swish'' = u(1-2s)+s (exact:
                                              // = 2pp + a*pp*(1-2s))
      const v2f c0  = uP  * W0P,  c1  = uP  * W1P;
      const v2f q00 = u2P * W00P, q01 = u2P * W01P, q11 = u2P * W11P;

      const v2f mP0 = LOv(M0), mP1 = LOv(M1), mP2 = LOv(M2);
      const v2f sP0 = HIv(M0), sP1 = HIv(M1), sP2 = HIv(M2);

      Jm[0][0] = FMA2(c0,  mP0, Jm[0][0]);  Jm[0][1] = FMA2(c1,  mP0, Jm[0][1]);
      Js[0][0] = FMA2(c0,  sP0, Js[0][0]);  Js[0][1] = FMA2(c1,  sP0, Js[0][1]);
      Km[0][0] = FMA2(q00, mP0, Km[0][0]);  Km[0][1] = FMA2(q01, mP0, Km[0][1]);
      Km[0][2] = FMA2(q11, mP0, Km[0][2]);
      Ks[0][0] = FMA2(q00, sP0, Ks[0][0]);  Ks[0][1] = FMA2(q01, sP0, Ks[0][1]);
      Ks[0][2] = FMA2(q11, sP0, Ks[0][2]);

      Jm[1][0] = FMA2(c0,  mP1, Jm[1][0]);  Jm[1][1] = FMA2(c1,  mP1, Jm[1][1]);
      Js[1][0] = FMA2(c0,  sP1, Js[1][0]);  Js[1][1] = FMA2(c1,  sP1, Js[1][1]);
      Km[1][0] = FMA2(q00, mP1, Km[1][0]);  Km[1][1] = FMA2(q01, mP1, Km[1][1]);
      Km[1][2] = FMA2(q11, mP1, Km[1][2]);
      Ks[1][0] = FMA2(q00, sP1, Ks[1][0]);  Ks[1][1] = FMA2(q01, sP1, Ks[1][1]);
      Ks[1][2] = FMA2(q11, sP1, Ks[1][2]);

      Jm[2][0] = FMA2(c0,  mP2, Jm[2][0]);  Jm[2][1] = FMA2(c1,  mP2, Jm[2][1]);
      Js[2][0] = FMA2(c0,  sP2, Js[2][0]);  Js[2][1] = FMA2(c1,  sP2, Js[2][1]);
      Km[2][0] = FMA2(q00, mP2, Km[2][0]);  Km[2][1] = FMA2(q01, mP2, Km[2][1]);
      Km[2][2] = FMA2(q11, mP2, Km[2][2]);
      Ks[2][0] = FMA2(q00, sP2, Ks[2][0]);  Ks[2][1] = FMA2(q01, sP2, Ks[2][1]);
      Ks[2][2] = FMA2(q11, sP2, Ks[2][2]);
    }

    // fold even/odd-j partials, then complete the j-sums across the quad
    float JmS[3][2], JsS[3][2], KmS[3][3], KsS[3][3];
    #pragma unroll
    for (int o = 0; o < 3; ++o) {
      JmS[o][0]=hqreduce(Jm[o][0]); JmS[o][1]=hqreduce(Jm[o][1]);
      JsS[o][0]=hqreduce(Js[o][0]); JsS[o][1]=hqreduce(Js[o][1]);
      KmS[o][0]=hqreduce(Km[o][0]); KmS[o][1]=hqreduce(Km[o][1]); KmS[o][2]=hqreduce(Km[o][2]);
      KsS[o][0]=hqreduce(Ks[o][0]); KsS[o][1]=hqreduce(Ks[o][1]); KsS[o][2]=hqreduce(Ks[o][2]);
    }

    // G = J^T J (2x2 sym)
    float G00=0.f, G01=0.f, G11=0.f;
    #pragma unroll
    for (int o = 0; o < 3; ++o) {
      G00 += JmS[o][0]*JmS[o][0] + JsS[o][0]*JsS[o][0];
      G01 += JmS[o][0]*JmS[o][1] + JsS[o][0]*JsS[o][1];
      G11 += JmS[o][1]*JmS[o][1] + JsS[o][1]*JsS[o][1];
    }
    // D[c][l] = dG[km]/dz_l (sym in k,m)
    float D00=0.f, D01=0.f, D10=0.f, D11=0.f, D20=0.f, D21=0.f;
    #pragma unroll
    for (int o = 0; o < 3; ++o) {
      D00 += 2.f*(KmS[o][0]*JmS[o][0] + KsS[o][0]*JsS[o][0]);
      D01 += 2.f*(KmS[o][1]*JmS[o][0] + KsS[o][1]*JsS[o][0]);
      D10 += KmS[o][0]*JmS[o][1] + JmS[o][0]*KmS[o][1] + KsS[o][0]*JsS[o][1] + JsS[o][0]*KsS[o][1];
      D11 += KmS[o][1]*JmS[o][1] + JmS[o][0]*KmS[o][2] + KsS[o][1]*JsS[o][1] + JsS[o][0]*KsS[o][2];
      D20 += 2.f*(KmS[o][1]*JmS[o][1] + KsS[o][1]*JsS[o][1]);
      D21 += 2.f*(KmS[o][2]*JmS[o][1] + KsS[o][2]*JsS[o][1]);
    }
    const float det = fmaf(G00, G11, -G01*G01);
    const float id  = __builtin_amdgcn_rcpf(det);
    const float i00 = G11*id, i01 = -G01*id, i11 = G00*id;
    // drift via S/P contraction (symbolically identical to the T/Chris form):
    //   S_m = ginv_jk Dg[j,m,k], P_m = ginv_jk Dg[j,k,m]
    //   dr_i = 0.25 * ginv_im * (2 S_m - P_m)
    const float S0 = fmaf(i00, D00, fmaf(i01, D01 + D10, i11 * D11));
    const float S1 = fmaf(i00, D10, fmaf(i01, D11 + D20, i11 * D21));
    const float i01d = i01 + i01;
    const float P0 = fmaf(i00, D00, fmaf(i01d, D10, i11 * D20));
    const float P1 = fmaf(i00, D01, fmaf(i01d, D11, i11 * D21));
    const float R0 = fmaf(0.5f, S0, -0.25f * P0);
    const float R1 = fmaf(0.5f, S1, -0.25f * P1);
    const float dr0 = fmaf(i00, R0, i01 * R1);
    const float dr1 = fmaf(i01, R0, i11 * R1);

    const float dw0 = sdt*nz.x, dw1 = sdt*nz.y;
    z0 += dr0 + i00*dw0 + i01*dw1;   // + ginv @ dW
    z1 += dr1 + i01*dw0 + i11*dw1;
  }

  // ---- final decode on z ----
  v2f MSm[3], MSs[3];
  #pragma unroll
  for (int o = 0; o < 3; ++o) { MSm[o] = splat(0.f); MSs[o] = splat(0.f); }
  const v2f zf0 = splat(z0), zf1 = splat(z1);
  {
    const v4f* R = Rq + pbase * 6;
    #pragma unroll 2
    for (int t = 0; t < LPP; ++t, R += 6) {
      const v4f A  = R[0];
      const v4f B  = R[1];
      const v4f M0 = R[3], M1 = R[4], M2 = R[5];
      v2f aP = FMA2(zf0, LOv(A), FMA2(zf1, HIv(A), LOv(B)));
      v2f eP;   eP.x   = __expf(-aP.x);               eP.y   = __expf(-aP.y);
      v2f dP = splat(1.f) + eP;
      v2f sigP; sigP.x = __builtin_amdgcn_rcpf(dP.x); sigP.y = __builtin_amdgcn_rcpf(dP.y);
      const v2f hP = aP * sigP;
      MSm[0] = FMA2(hP, LOv(M0), MSm[0]);  MSs[0] = FMA2(hP, HIv(M0), MSs[0]);
      MSm[1] = FMA2(hP, LOv(M1), MSm[1]);  MSs[1] = FMA2(hP, HIv(M1), MSs[1]);
      MSm[2] = FMA2(hP, LOv(M2), MSm[2]);  MSs[2] = FMA2(hP, HIv(M2), MSs[2]);
    }
  }
  // reductions must run on all quad lanes (DPP reads masked lanes as 0)
  float mu[3], ls[3];
  #pragma unroll
  for (int o = 0; o < 3; ++o) { mu[o] = hqreduce(MSm[o]); ls[o] = hqreduce(MSs[o]); }

  if (l == 0) {
    out[OFF_Z + pg*2+0] = z0;
    out[OFF_Z + pg*2+1] = z1;
    #pragma unroll
    for (int o = 0; o < 3; ++o) {
      out[OFF_MUXZ + pg*3 + o] = mu[o] + bdmu[o];
      out[OFF_LSXZ + pg*3 + o] = ls[o] + bds[o];
    }
  }
}

extern "C" void kernel_launch(void* const* d_in, const int* in_sizes, int n_in,
                              void* d_out, int out_size, void* d_ws, size_t ws_size,
                              hipStream_t stream) {
  (void)in_sizes; (void)n_in; (void)d_ws; (void)ws_size; (void)out_size;
  const float* x    = (const float*)d_in[0];
  const float* We1  = (const float*)d_in[1];
  const float* be1  = (const float*)d_in[2];
  const float* We2  = (const float*)d_in[3];
  const float* be2  = (const float*)d_in[4];
  const float* Wmu  = (const float*)d_in[5];
  const float* bmu  = (const float*)d_in[6];
  const float* Wlt  = (const float*)d_in[7];
  const float* blt  = (const float*)d_in[8];
  const float* Wd1  = (const float*)d_in[9];
  const float* bd1  = (const float*)d_in[10];
  const float* Wdmu = (const float*)d_in[11];
  const float* bdmu = (const float*)d_in[12];
  const float* Wds  = (const float*)d_in[13];
  const float* bds  = (const float*)d_in[14];
  const float* bmz  = (const float*)d_in[15];
  const float* blz  = (const float*)d_in[16];
  const float* noise= (const float*)d_in[17];
  float* out = (float*)d_out;

  vaebm_kernel<<<512, 256, 0, stream>>>(x, We1, be1, We2, be2, Wmu, bmu, Wlt, blt,
                                        Wd1, bd1, Wdmu, bdmu, Wds, bds,
                                        bmz, blz, noise, out);
}